// Round 3
// baseline (238.288 us; speedup 1.0000x reference)
//
#include <hip/hip_runtime.h>
#include <stdint.h>

// Problem constants (B=64, S=512 -> 32768 tokens)
#define N_TOK 32768
#define DIN   512
#define DFF   1024
#define MPAD  33792   // 32768 + 8*128 worst-case bucket padding

// fp8 rotation convention: within each 128B K-window, row data is rotated by
// (row mod 16)*8 bytes: phys = (k & ~127) + (((k&127) + (row&15)*8) & 127).
// Same permutation on A-rows and B-rows => dot product unchanged. Staging is
// then a linear aligned copy; fragment reads cover all 32 banks (conflict-free).
__device__ __forceinline__ int rotk(int k, int row) {
    return (k & ~127) + (((k & 127) + ((row & 15) << 3)) & 127);
}

typedef __attribute__((ext_vector_type(8))) short bf16x8;
typedef __attribute__((ext_vector_type(4))) float f32x4;

__device__ __forceinline__ unsigned short f2bf(float f) {
    union { float f; unsigned int u; } v; v.f = f;
    unsigned int u = v.u;
    return (unsigned short)((u + 0x7FFFu + ((u >> 16) & 1u)) >> 16);
}
__device__ __forceinline__ float bf2f(unsigned int bits) {
    union { unsigned int u; float f; } v; v.u = bits << 16; return v.f;
}
// pack 4 floats -> 4 OCP e4m3 bytes (hw cvt, saturating)
__device__ __forceinline__ unsigned int pk4_fp8(float a, float b, float c, float d) {
    int v = __builtin_amdgcn_cvt_pk_fp8_f32(a, b, 0, false);
    v = __builtin_amdgcn_cvt_pk_fp8_f32(c, d, v, true);
    return (unsigned int)v;
}
__device__ __forceinline__ unsigned char f2fp8(float a) {
    return (unsigned char)(__builtin_amdgcn_cvt_pk_fp8_f32(a, a, 0, false) & 0xFF);
}

// async 16B global -> LDS (wave-uniform LDS base + lane*16 pattern)
__device__ __forceinline__ void async16(const void* g, void* l) {
    __builtin_amdgcn_global_load_lds(
        (const __attribute__((address_space(1))) void*)g,
        (__attribute__((address_space(3))) void*)l, 16, 0, 0);
}

// ---------------- merged prep: tokens + weights + perm-pad in ONE launch -------
__global__ void prep_kernel(const float* __restrict__ x,
                            unsigned short* __restrict__ Xb,
                            unsigned char* __restrict__ Xb8,
                            const int* __restrict__ types,
                            int* __restrict__ blockhist,
                            const float* __restrict__ Wp,
                            const float* __restrict__ Wt,
                            const float* __restrict__ Wc,
                            unsigned char* __restrict__ Wp8,
                            unsigned char* __restrict__ Wt8,
                            unsigned short* __restrict__ WcT,
                            int* __restrict__ perm) {
    __shared__ float tile[32][33];
    __shared__ int lc[8];
    const int b = blockIdx.x, tid = threadIdx.x;
    if (b < 16384) {
        const int i = b * 1024 + tid * 4;
        float4 v = *(const float4*)(x + i);
        ushort4 o;
        o.x = f2bf(v.x); o.y = f2bf(v.y); o.z = f2bf(v.z); o.w = f2bf(v.w);
        *(ushort4*)(Xb + i) = o;
        const int row = i >> 9;             // DIN=512
        const int k   = i & 511;
        *(unsigned int*)(Xb8 + (size_t)row * DIN + rotk(k, row)) = pk4_fp8(v.x, v.y, v.z, v.w);
        if (b < 64) {
            if (tid < 8) lc[tid] = 0;
            __syncthreads();
            atomicAdd(&lc[types[b * 512 + tid]], 1);
            atomicAdd(&lc[types[b * 512 + 256 + tid]], 1);
            __syncthreads();
            if (tid < 8) blockhist[b * 8 + tid] = lc[tid];
        }
    } else if (b < 26624) {
        const int r = b - 16384;
        const int z = r >> 10;
        const int bx = r & 31, by = (r >> 5) & 31;
        const int tx = tid & 31, ty = tid >> 5;
        const float* s; int K, N;
        if (z == 0)      { s = Wp;                          K = 512;  N = 1024; }
        else if (z <= 8) { s = Wt + (size_t)(z-1)*DIN*DFF;  K = 1024; N = 512; }
        else             { s = Wc;                          K = 512;  N = 512; }
        const int n0 = bx * 32, k0 = by * 32;
        if (n0 >= N || k0 >= K) return;
        for (int i = ty; i < 32; i += 8)
            tile[i][tx] = s[(size_t)(k0 + i) * N + n0 + tx];
        __syncthreads();
        if (z <= 8) {
            // 4B-packed fp8 store: thread owns (1 n, 4 consecutive k)
            unsigned char* d = (z == 0) ? Wp8 : (Wt8 + (size_t)(z-1)*DIN*DFF);
            const int nl = tid >> 3;            // 0..31
            const int k4 = (tid & 7) << 2;      // 0,4,..,28
            const int n  = n0 + nl;
            const int kk = k0 + k4;
            unsigned int pk = pk4_fp8(tile[k4 + 0][nl] * 64.f, tile[k4 + 1][nl] * 64.f,
                                      tile[k4 + 2][nl] * 64.f, tile[k4 + 3][nl] * 64.f);
            *(unsigned int*)(d + (size_t)n * K + rotk(kk, n)) = pk;
        } else {
            for (int i = ty; i < 32; i += 8)
                WcT[(size_t)(n0 + i) * K + k0 + tx] = f2bf(tile[tx][i]);
        }
    } else {
        perm[(b - 26624) * 256 + tid] = -1;
    }
}

// ---- atomic-free scatter: 64 blocks x 512 threads, deterministic placement ----
__global__ void scatter_kernel(const int* __restrict__ types,
                               const int* __restrict__ blockhist,
                               int* __restrict__ perm,
                               int* __restrict__ invperm,
                               float* __restrict__ outz,
                               int* __restrict__ po_out) {
    __shared__ int tots[8], base[8], fill[8];
    const int blk = blockIdx.x;            // 64
    const int tid = threadIdx.x;           // 512
    const int i = blk * 512 + tid;
    outz[i] = 0.f;
    int pre = 0;
    if (tid < 8) {
        int total = 0;
        for (int j = 0; j < 64; j++) {
            int v = blockhist[j * 8 + tid];
            if (j < blk) pre += v;
            total += v;
        }
        tots[tid] = total;
    }
    __syncthreads();
    if (tid < 8) {
        int off = 0, pob = 0;
        #pragma unroll
        for (int t2 = 0; t2 < 8; t2++) {
            if (t2 == tid) pob = off;
            off += ((tots[t2] + 127) >> 7) << 7;
        }
        base[tid] = pob + pre;
        fill[tid] = 0;
        if (blk == 0) {
            po_out[tid] = pob;
            if (tid == 0) po_out[8] = off;
        }
    }
    __syncthreads();
    const int t = types[i];
    const int r = atomicAdd(&fill[t], 1);  // LDS atomic: intra-block rank
    const int p = base[t] + r;
    perm[p] = i;
    invperm[i] = p;
}

// ---------- GEMM1 (fp8): 256x256 tile, BK=128, 8 waves, phased schedule --------
// (R1: neutral vs 128^2; kept, bit-identical. Untouched this round for clean
// attribution of the GEMM2 change.)
__global__ __launch_bounds__(512, 2)
void gemm1_fp8_8ph(const unsigned char* __restrict__ A,
                   const unsigned char* __restrict__ B,
                   unsigned char* __restrict__ C8,
                   const int* __restrict__ invperm) {
    __shared__ unsigned char As[2][256 * 128];
    __shared__ unsigned char Bs[2][256 * 128];
    __shared__ int ptile[256];

    const int tid  = threadIdx.x;
    const int wave = tid >> 6;
    const int lane = tid & 63;
    const int quad = lane >> 4;
    const int tl   = lane & 15;

    const int lin  = blockIdx.x;                 // 0..511
    const int sid  = (lin & 7) * 64 + (lin >> 3); // bijective XCD swizzle
    const int m0   = (sid >> 2) * 256;           // token tile
    const int n0   = (sid & 3) * 256;            // ff tile

    const int wm = (wave & 1) * 128;             // wave: 128 rows x 64 cols
    const int wn = (wave >> 1) * 64;

    if (tid < 256) ptile[tid] = invperm[m0 + tid];

    f32x4 acc[8][4];
    #pragma unroll
    for (int i = 0; i < 8; i++)
        #pragma unroll
        for (int j = 0; j < 4; j++)
            acc[i][j] = (f32x4){0.f, 0.f, 0.f, 0.f};

    // prologue: stage K-tile 0 into slot 0 (8 chunks/thread: 4 A + 4 B)
    #pragma unroll
    for (int ci = 0; ci < 8; ++ci) {
        const int c = ci * 512 + tid;
        if (ci < 4) {
            const int row = c >> 3, j = c & 7;
            async16(A + (size_t)(m0 + row) * 512 + j * 16, &As[0][c * 16]);
        } else {
            const int c2 = c - 2048;
            const int row = c2 >> 3, j = c2 & 7;
            async16(B + (size_t)(n0 + row) * 512 + j * 16, &Bs[0][c2 * 16]);
        }
    }
    asm volatile("s_waitcnt vmcnt(0)" ::: "memory");
    __builtin_amdgcn_s_barrier();
    asm volatile("" ::: "memory");

    for (int t = 0; t < 4; ++t) {                 // K = 512, BK = 128
        const unsigned char* Asl = As[t & 1];
        const unsigned char* Bsl = Bs[t & 1];
        unsigned char* Asn = As[(t + 1) & 1];
        unsigned char* Bsn = Bs[(t + 1) & 1];
        const int k0n = (t + 1) * 128;
        const bool st = (t < 3);
        #pragma unroll
        for (int ph = 0; ph < 8; ++ph) {          // ph = ks*2 + mh
            const int ks = ph >> 1, mh = ph & 1;
            const int o = (ks * 32 + quad * 8 + tl * 8) & 127;  // rotated frag offset
            long af[4], bfr[4];
            #pragma unroll
            for (int mt = 0; mt < 4; ++mt)
                af[mt] = *(const long*)(Asl + (wm + mh * 64 + mt * 16 + tl) * 128 + o);
            #pragma unroll
            for (int nt = 0; nt < 4; ++nt)
                bfr[nt] = *(const long*)(Bsl + (wn + nt * 16 + tl) * 128 + o);
            if (st && ph < 4) {
                // prefetch K-tile t+1 into the OTHER slot: 2 chunks/phase
                #pragma unroll
                for (int u = 0; u < 2; ++u) {
                    const int cidx = ph * 2 + u;      // 0..7 (compile-time)
                    const int c = cidx * 512 + tid;
                    if (cidx < 4) {
                        const int row = c >> 3, j = c & 7;
                        async16(A + (size_t)(m0 + row) * 512 + k0n + j * 16, Asn + c * 16);
                    } else {
                        const int c2 = c - 2048;
                        const int row = c2 >> 3, j = c2 & 7;
                        async16(B + (size_t)(n0 + row) * 512 + k0n + j * 16, Bsn + c2 * 16);
                    }
                }
            }
            __builtin_amdgcn_s_barrier();
            asm volatile("" ::: "memory");
            __builtin_amdgcn_s_setprio(1);
            #pragma unroll
            for (int mt = 0; mt < 4; ++mt)
                #pragma unroll
                for (int nt = 0; nt < 4; ++nt)
                    acc[mh * 4 + mt][nt] = __builtin_amdgcn_mfma_f32_16x16x32_fp8_fp8(
                        bfr[nt], af[mt], acc[mh * 4 + mt][nt], 0, 0, 0);  // swapped: D[n][tok]
            __builtin_amdgcn_s_setprio(0);
            if (ph == 7) asm volatile("s_waitcnt vmcnt(0)" ::: "memory");
            __builtin_amdgcn_s_barrier();
            asm volatile("" ::: "memory");
        }
    }

    // epilogue: lane holds 4 consecutive n (regs) for token tl; scatter via invperm
    #pragma unroll
    for (int mh = 0; mh < 2; ++mh)
        #pragma unroll
        for (int mt = 0; mt < 4; ++mt) {
            const int p = ptile[wm + mh * 64 + mt * 16 + tl];   // bucket position
            const size_t rowbase = (size_t)p * DFF;
            const int prot = (p & 15) << 3;
            #pragma unroll
            for (int nt = 0; nt < 4; ++nt) {
                const int off = wn + nt * 16 + quad * 4;        // 0..255 in n-tile
                unsigned int pk = pk4_fp8(fmaxf(acc[mh * 4 + mt][nt][0], 0.f) * 0.125f,
                                          fmaxf(acc[mh * 4 + mt][nt][1], 0.f) * 0.125f,
                                          fmaxf(acc[mh * 4 + mt][nt][2], 0.f) * 0.125f,
                                          fmaxf(acc[mh * 4 + mt][nt][3], 0.f) * 0.125f);
                const int phys = (off & ~127) + (((off & 127) + prot) & 127);
                *(unsigned int*)(C8 + rowbase + n0 + phys) = pk;
            }
        }
}

// ---------- GEMM2 (fp8, routed): 128x128, BK=128, DOUBLE-BUF + COUNTED VMCNT ---
// R3: T4 applied to the measured schedule-bound dispatch. Same tile geometry,
// fragment rotation, MFMA order, grid + XCD band swizzle as the proven kernel
// (bit-identical accumulation). Structural changes only:
//  - 2 LDS slots (64KB total -> still 2 blocks/CU);
//  - raw s_barrier (no compiler vmcnt(0) drain per barrier);
//  - tile t+2 issued immediately after slot t is fully read; end-of-tile wait
//    is vmcnt(8) = "previous tile landed, next tile's 8 loads stay in flight".
//    Loads get a full tile duration to land instead of being drained at issue.
//  - setprio(1) around each 16-MFMA cluster (T5).
// All phases are read-only on the slot; the only hazards are at tile
// boundaries, covered by the two barriers. All control flow is block-uniform.
__global__ __launch_bounds__(256, 2)
void gemm2_fp8_dbuf(const unsigned char* __restrict__ A,   // Xff8 [MPAD][1024]
                    const unsigned char* __restrict__ B,   // Wt8 [8][512][1024]
                    unsigned short* __restrict__ Cb,       // Xb (residual RMW)
                    const unsigned short* __restrict__ xres,
                    const int* __restrict__ perm,
                    const int* __restrict__ po) {
    __shared__ __align__(16) unsigned char As[2][128 * 128];
    __shared__ __align__(16) unsigned char Bs[2][128 * 128];
    __shared__ int ptile[128];

    const int tid  = threadIdx.x;
    const int wave = tid >> 6;
    const int lane = tid & 63;
    const int quad = lane >> 4;
    const int tl   = lane & 15;
    // 1056 blocks; XCD-band swizzle (1056 % 8 == 0, bijective)
    const int sid = (blockIdx.x & 7) * 132 + (blockIdx.x >> 3);
    const int m0 = (sid >> 2) * 128;
    const int n0 = (sid & 3) * 128;
    const int wm = (wave & 1) * 64;
    const int wn = (wave >> 1) * 64;

    if (m0 >= po[8]) return;                  // fully-padded tail block (pre-barrier)
    int bsel = 0;
    #pragma unroll
    for (int i = 1; i < 8; i++) bsel += (m0 >= po[i]) ? 1 : 0;
    const unsigned char* Bp = B + (size_t)bsel * (DIN * DFF);

    if (tid < 128) ptile[tid] = perm[m0 + tid];

    f32x4 acc[4][4];
    #pragma unroll
    for (int i = 0; i < 4; i++)
        #pragma unroll
        for (int j = 0; j < 4; j++)
            acc[i][j] = (f32x4){0.f, 0.f, 0.f, 0.f};

    // stage K-tile kt (8 chunks/thread = 8 vmcnt per wave) into slot s
    auto stage = [&](int kt, int s) {
        const int k0 = kt * 128;
        #pragma unroll
        for (int i = 0; i < 4; i++) {
            const int c = (i * 4 + wave) * 64 + lane;
            const int row = c >> 3, j = c & 7;
            async16(A + (size_t)(m0 + row) * 1024 + k0 + j * 16, &As[s][c * 16]);
        }
        #pragma unroll
        for (int i = 0; i < 4; i++) {
            const int c = (i * 4 + wave) * 64 + lane;
            const int row = c >> 3, j = c & 7;
            async16(Bp + (size_t)(n0 + row) * 1024 + k0 + j * 16, &Bs[s][c * 16]);
        }
    };

    // prologue: T0 -> slot0, T1 -> slot1; wait for T0 only (T1 stays in flight)
    stage(0, 0);
    stage(1, 1);
    asm volatile("s_waitcnt vmcnt(8) lgkmcnt(0)" ::: "memory");
    __builtin_amdgcn_s_barrier();
    asm volatile("" ::: "memory");

    for (int t = 0; t < 8; ++t) {             // K = 1024, BK = 128
        const unsigned char* Asl = As[t & 1];
        const unsigned char* Bsl = Bs[t & 1];
        #pragma unroll
        for (int ks = 0; ks < 4; ks++) {
            long af[4], bfr[4];
            const int o = (ks * 32 + quad * 8 + tl * 8) & 127;  // rotated frag offset
            #pragma unroll
            for (int mt = 0; mt < 4; mt++)
                af[mt] = *(const long*)(Asl + (wm + mt * 16 + tl) * 128 + o);
            #pragma unroll
            for (int nt = 0; nt < 4; nt++)
                bfr[nt] = *(const long*)(Bsl + (wn + nt * 16 + tl) * 128 + o);
            __builtin_amdgcn_s_setprio(1);
            #pragma unroll
            for (int mt = 0; mt < 4; mt++)
                #pragma unroll
                for (int nt = 0; nt < 4; nt++)
                    acc[mt][nt] = __builtin_amdgcn_mfma_f32_16x16x32_fp8_fp8(
                        bfr[nt], af[mt], acc[mt][nt], 0, 0, 0);  // swapped: D[n][tok]
            __builtin_amdgcn_s_setprio(0);
        }
        // all waves done reading slot t&1 (each wave's ds_reads were consumed
        // by its MFMA behind a compiler lgkmcnt before reaching this barrier)
        __builtin_amdgcn_s_barrier();
        asm volatile("" ::: "memory");
        if (t + 2 < 8) {
            stage(t + 2, t & 1);              // refill the slot just consumed
            // wait: T(t+1) landed (oldest 8), T(t+2)'s 8 stay in flight
            asm volatile("s_waitcnt vmcnt(8)" ::: "memory");
        } else {
            asm volatile("s_waitcnt vmcnt(0)" ::: "memory");  // tail: drain T7
        }
        __builtin_amdgcn_s_barrier();
        asm volatile("" ::: "memory");
    }

    // epilogue: lane holds 4 consecutive n (regs) for token tl; batched loads
    int toks[4];
    #pragma unroll
    for (int mt = 0; mt < 4; mt++) toks[mt] = ptile[wm + mt * 16 + tl];
    ushort4 rv[4][4];
    #pragma unroll
    for (int mt = 0; mt < 4; mt++) {
        if (toks[mt] < 0) continue;
        const size_t rowbase = (size_t)toks[mt] * DIN;
        #pragma unroll
        for (int nt = 0; nt < 4; nt++)
            rv[mt][nt] = *(const ushort4*)(xres + rowbase + n0 + wn + nt * 16 + quad * 4);
    }
    #pragma unroll
    for (int mt = 0; mt < 4; mt++) {
        if (toks[mt] < 0) continue;
        const size_t rowbase = (size_t)toks[mt] * DIN;
        #pragma unroll
        for (int nt = 0; nt < 4; nt++) {
            const int ncol = n0 + wn + nt * 16 + quad * 4;
            ushort4 o;
            o.x = f2bf(bf2f(rv[mt][nt].x) + fmaxf(acc[mt][nt][0], 0.f) * 0.001953125f);
            o.y = f2bf(bf2f(rv[mt][nt].y) + fmaxf(acc[mt][nt][1], 0.f) * 0.001953125f);
            o.z = f2bf(bf2f(rv[mt][nt].z) + fmaxf(acc[mt][nt][2], 0.f) * 0.001953125f);
            o.w = f2bf(bf2f(rv[mt][nt].w) + fmaxf(acc[mt][nt][3], 0.f) * 0.001953125f);
            *(ushort4*)(Cb + rowbase + ncol) = o;
        }
    }
}

// ------- bf16 GEMM3 + head (kept full precision): 128x256 tile, 512 thr --------
// out[tok] += relu(Xb @ W_c1) . w2   (atomicAdd partials per n-block)
// 1D grid + XCD-band swizzle (512 % 8 == 0).
__global__ __launch_bounds__(512, 4)
void gemm3_kernel(const unsigned short* __restrict__ A,
                  const unsigned short* __restrict__ B,
                  const float* __restrict__ w2,
                  float* __restrict__ outp,
                  int K, int ldA) {
    __shared__ unsigned short As[128 * 64];
    __shared__ unsigned short Bs[256 * 64];

    const int tid  = threadIdx.x;
    const int wave = tid >> 6;
    const int lane = tid & 63;
    const int quad = lane >> 4;
    const int tl   = lane & 15;
    const int sid = (blockIdx.x & 7) * 64 + (blockIdx.x >> 3);
    const int m0 = (sid >> 1) * 128;
    const int n0 = (sid & 1) * 256;
    const int wm = (wave & 1) * 64;
    const int wn = (wave >> 1) * 64;

    f32x4 acc[4][4];
    #pragma unroll
    for (int i = 0; i < 4; i++)
        #pragma unroll
        for (int j = 0; j < 4; j++)
            acc[i][j] = (f32x4){0.f, 0.f, 0.f, 0.f};

    for (int k0 = 0; k0 < K; k0 += 64) {
        __syncthreads();
        #pragma unroll
        for (int i = 0; i < 2; i++) {
            const int c   = (i * 8 + wave) * 64 + lane;
            const int row = c >> 3;
            const int gj  = (c & 7) ^ (row & 7);
            async16(A + (size_t)(m0 + row) * ldA + k0 + gj * 8, (char*)As + (size_t)c * 16);
        }
        #pragma unroll
        for (int i = 0; i < 4; i++) {
            const int c   = (i * 8 + wave) * 64 + lane;
            const int row = c >> 3;
            const int gj  = (c & 7) ^ (row & 7);
            async16(B + (size_t)(n0 + row) * K + k0 + gj * 8, (char*)Bs + (size_t)c * 16);
        }
        __syncthreads();

        #pragma unroll
        for (int ks = 0; ks < 2; ks++) {
            bf16x8 af[4], bfr[4];
            const int jc = ks * 4 + quad;
            #pragma unroll
            for (int t = 0; t < 4; t++) {
                const int r = wm + t * 16 + tl;
                af[t] = *(const bf16x8*)(As + (r * 8 + (jc ^ (r & 7))) * 8);
            }
            #pragma unroll
            for (int t = 0; t < 4; t++) {
                const int r = wn + t * 16 + tl;
                bfr[t] = *(const bf16x8*)(Bs + (r * 8 + (jc ^ (r & 7))) * 8);
            }
            #pragma unroll
            for (int mt = 0; mt < 4; mt++)
                #pragma unroll
                for (int nt = 0; nt < 4; nt++)
                    acc[mt][nt] = __builtin_amdgcn_mfma_f32_16x16x32_bf16(
                        bfr[nt], af[mt], acc[mt][nt], 0, 0, 0);
        }
    }

    float4 w2v[4];
    #pragma unroll
    for (int nt = 0; nt < 4; nt++)
        w2v[nt] = *(const float4*)(w2 + n0 + wn + nt * 16 + quad * 4);
    #pragma unroll
    for (int mt = 0; mt < 4; mt++) {
        float s = 0.f;
        #pragma unroll
        for (int nt = 0; nt < 4; nt++) {
            s += fmaxf(acc[mt][nt][0], 0.f) * w2v[nt].x;
            s += fmaxf(acc[mt][nt][1], 0.f) * w2v[nt].y;
            s += fmaxf(acc[mt][nt][2], 0.f) * w2v[nt].z;
            s += fmaxf(acc[mt][nt][3], 0.f) * w2v[nt].w;
        }
        s += __shfl_down(s, 32);
        s += __shfl_down(s, 16);
        if (lane < 16) atomicAdd(&outp[m0 + wm + mt * 16 + lane], s);
    }
}

extern "C" void kernel_launch(void* const* d_in, const int* in_sizes, int n_in,
                              void* d_out, int out_size, void* d_ws, size_t ws_size,
                              hipStream_t stream) {
    const float* x      = (const float*)d_in[0];
    const int*   types  = (const int*)d_in[1];
    const float* W_pre  = (const float*)d_in[2];
    const float* W_types= (const float*)d_in[3];
    const float* W_c1   = (const float*)d_in[4];
    const float* W_c2   = (const float*)d_in[5];
    float* out = (float*)d_out;

    // workspace layout (~91 MB):
    char* ws = (char*)d_ws;
    unsigned short* Xb  = (unsigned short*)(ws);                    // bf16 [32768][512], becomes X_res
    unsigned char*  Xff8= (unsigned char*)(ws + 33554432ull);       // fp8 [MPAD][1024] = 8*x_, bucket order, k-rotated
    unsigned char*  Xb8 = (unsigned char*)(ws + 68157440ull);       // fp8 [32768][512] = x, k-rotated
    unsigned char*  Wp8 = (unsigned char*)(ws + 84934656ull);       // fp8 [1024][512] (x64, rotated)
    unsigned char*  Wt8 = (unsigned char*)(ws + 85458944ull);       // fp8 [8][512][1024] (x64, rotated)
    unsigned short* WcT = (unsigned short*)(ws + 89653248ull);      // bf16 [512][512]
    int* perm           = (int*)(ws + 90177536ull);                  // MPAD ints
    int* invperm        = (int*)(ws + 90312704ull);                  // N_TOK ints
    int* po             = (int*)(ws + 90443776ull);                  // 9 ints (padded offsets)
    int* blockhist      = po + 16;                                   // 64*8 ints

    // 1) merged prep: tokens [0,16384), weights [16384,26624), perm-pad [26624,26756)
    prep_kernel<<<26756, 256, 0, stream>>>(x, Xb, Xb8, types, blockhist,
                                           W_pre, W_types, W_c1, Wp8, Wt8, WcT, perm);
    // 2) deterministic scatter + po publish + out zero
    scatter_kernel<<<64, 512, 0, stream>>>(types, blockhist, perm, invperm, out, po);
    // 3) GEMM1 (fp8, 8-phase 256^2): Xff8[invperm[tok]] = fp8(8 * relu(x @ W_pre))
    gemm1_fp8_8ph<<<512, 512, 0, stream>>>(Xb8, Wp8, Xff8, invperm);
    // 4) GEMM2 (fp8, routed, dbuf+counted-vmcnt): Xb = bf16(Xb + relu(Xff8 @ Wt8[b]) / 512)
    gemm2_fp8_dbuf<<<1056, 256, 0, stream>>>(Xff8, Wt8, Xb, Xb, perm, po);
    // 5) GEMM3 + head (bf16, XCD-banded 1D grid): out = relu(Xb @ W_c1) @ W_c2
    gemm3_kernel<<<512, 512, 0, stream>>>(
        Xb, WcT, W_c2, out, 512, 512);
}

// Round 4
// 233.678 us; speedup vs baseline: 1.0197x; 1.0197x over previous
//
#include <hip/hip_runtime.h>
#include <stdint.h>

// Problem constants (B=64, S=512 -> 32768 tokens)
#define N_TOK 32768
#define DIN   512
#define DFF   1024
#define MPAD  33792   // 32768 + 8*128 worst-case bucket padding

// fp8 rotation convention: within each 128B K-window, row data is rotated by
// (row mod 16)*8 bytes: phys = (k & ~127) + (((k&127) + (row&15)*8) & 127).
// Same permutation on A-rows and B-rows => dot product unchanged. Staging is
// then a linear aligned copy; fragment reads cover all 32 banks (conflict-free).
__device__ __forceinline__ int rotk(int k, int row) {
    return (k & ~127) + (((k & 127) + ((row & 15) << 3)) & 127);
}

typedef __attribute__((ext_vector_type(8))) short bf16x8;
typedef __attribute__((ext_vector_type(4))) float f32x4;

__device__ __forceinline__ unsigned short f2bf(float f) {
    union { float f; unsigned int u; } v; v.f = f;
    unsigned int u = v.u;
    return (unsigned short)((u + 0x7FFFu + ((u >> 16) & 1u)) >> 16);
}
__device__ __forceinline__ float bf2f(unsigned int bits) {
    union { unsigned int u; float f; } v; v.u = bits << 16; return v.f;
}
// pack 4 floats -> 4 OCP e4m3 bytes (hw cvt, saturating)
__device__ __forceinline__ unsigned int pk4_fp8(float a, float b, float c, float d) {
    int v = __builtin_amdgcn_cvt_pk_fp8_f32(a, b, 0, false);
    v = __builtin_amdgcn_cvt_pk_fp8_f32(c, d, v, true);
    return (unsigned int)v;
}
__device__ __forceinline__ unsigned char f2fp8(float a) {
    return (unsigned char)(__builtin_amdgcn_cvt_pk_fp8_f32(a, a, 0, false) & 0xFF);
}

// async 16B global -> LDS (wave-uniform LDS base + lane*16 pattern)
__device__ __forceinline__ void async16(const void* g, void* l) {
    __builtin_amdgcn_global_load_lds(
        (const __attribute__((address_space(1))) void*)g,
        (__attribute__((address_space(3))) void*)l, 16, 0, 0);
}

// ---------------- merged prep: tokens + weights + perm-pad in ONE launch -------
__global__ void prep_kernel(const float* __restrict__ x,
                            unsigned short* __restrict__ Xb,
                            unsigned char* __restrict__ Xb8,
                            const int* __restrict__ types,
                            int* __restrict__ blockhist,
                            const float* __restrict__ Wp,
                            const float* __restrict__ Wt,
                            const float* __restrict__ Wc,
                            unsigned char* __restrict__ Wp8,
                            unsigned char* __restrict__ Wt8,
                            unsigned short* __restrict__ WcT,
                            int* __restrict__ perm) {
    __shared__ float tile[32][33];
    __shared__ int lc[8];
    const int b = blockIdx.x, tid = threadIdx.x;
    if (b < 16384) {
        const int i = b * 1024 + tid * 4;
        float4 v = *(const float4*)(x + i);
        ushort4 o;
        o.x = f2bf(v.x); o.y = f2bf(v.y); o.z = f2bf(v.z); o.w = f2bf(v.w);
        *(ushort4*)(Xb + i) = o;
        const int row = i >> 9;             // DIN=512
        const int k   = i & 511;
        *(unsigned int*)(Xb8 + (size_t)row * DIN + rotk(k, row)) = pk4_fp8(v.x, v.y, v.z, v.w);
        if (b < 64) {
            if (tid < 8) lc[tid] = 0;
            __syncthreads();
            atomicAdd(&lc[types[b * 512 + tid]], 1);
            atomicAdd(&lc[types[b * 512 + 256 + tid]], 1);
            __syncthreads();
            if (tid < 8) blockhist[b * 8 + tid] = lc[tid];
        }
    } else if (b < 26624) {
        const int r = b - 16384;
        const int z = r >> 10;
        const int bx = r & 31, by = (r >> 5) & 31;
        const int tx = tid & 31, ty = tid >> 5;
        const float* s; int K, N;
        if (z == 0)      { s = Wp;                          K = 512;  N = 1024; }
        else if (z <= 8) { s = Wt + (size_t)(z-1)*DIN*DFF;  K = 1024; N = 512; }
        else             { s = Wc;                          K = 512;  N = 512; }
        const int n0 = bx * 32, k0 = by * 32;
        if (n0 >= N || k0 >= K) return;
        for (int i = ty; i < 32; i += 8)
            tile[i][tx] = s[(size_t)(k0 + i) * N + n0 + tx];
        __syncthreads();
        if (z <= 8) {
            // 4B-packed fp8 store: thread owns (1 n, 4 consecutive k)
            unsigned char* d = (z == 0) ? Wp8 : (Wt8 + (size_t)(z-1)*DIN*DFF);
            const int nl = tid >> 3;            // 0..31
            const int k4 = (tid & 7) << 2;      // 0,4,..,28
            const int n  = n0 + nl;
            const int kk = k0 + k4;
            unsigned int pk = pk4_fp8(tile[k4 + 0][nl] * 64.f, tile[k4 + 1][nl] * 64.f,
                                      tile[k4 + 2][nl] * 64.f, tile[k4 + 3][nl] * 64.f);
            *(unsigned int*)(d + (size_t)n * K + rotk(kk, n)) = pk;
        } else {
            for (int i = ty; i < 32; i += 8)
                WcT[(size_t)(n0 + i) * K + k0 + tx] = f2bf(tile[tx][i]);
        }
    } else {
        perm[(b - 26624) * 256 + tid] = -1;
    }
}

// ---- atomic-free scatter: 64 blocks x 512 threads, deterministic placement ----
__global__ void scatter_kernel(const int* __restrict__ types,
                               const int* __restrict__ blockhist,
                               int* __restrict__ perm,
                               int* __restrict__ invperm,
                               float* __restrict__ outz,
                               int* __restrict__ po_out) {
    __shared__ int tots[8], base[8], fill[8];
    const int blk = blockIdx.x;            // 64
    const int tid = threadIdx.x;           // 512
    const int i = blk * 512 + tid;
    outz[i] = 0.f;
    int pre = 0;
    if (tid < 8) {
        int total = 0;
        for (int j = 0; j < 64; j++) {
            int v = blockhist[j * 8 + tid];
            if (j < blk) pre += v;
            total += v;
        }
        tots[tid] = total;
    }
    __syncthreads();
    if (tid < 8) {
        int off = 0, pob = 0;
        #pragma unroll
        for (int t2 = 0; t2 < 8; t2++) {
            if (t2 == tid) pob = off;
            off += ((tots[t2] + 127) >> 7) << 7;
        }
        base[tid] = pob + pre;
        fill[tid] = 0;
        if (blk == 0) {
            po_out[tid] = pob;
            if (tid == 0) po_out[8] = off;
        }
    }
    __syncthreads();
    const int t = types[i];
    const int r = atomicAdd(&fill[t], 1);  // LDS atomic: intra-block rank
    const int p = base[t] + r;
    perm[p] = i;
    invperm[i] = p;
}

// ---------- fp8 GEMM (R4): 128x128 tile, BK=128, 16 WAVES (1024 thr) -----------
// Proven 2-barrier structure (R0/R2), re-partitioned for the register/occupancy
// cliff: per-wave output 32x32 -> acc[2][2] = 16 f32. Combined VGPR+AGPR ~50
// (<= 64) -> 8 waves/SIMD -> 2 blocks/CU = 32 waves/CU (2x the old 16).
// Mechanism: m114 cross-block overlap is what hides the per-step vmcnt(0)
// barrier drain in this structure; it scales with resident waves.
// Staging: exactly 1 A-chunk + 1 B-chunk (16B) per thread per K-step, linear.
// Fragment rotation, MFMA operand order, and per-element accumulation order
// are verbatim from the proven kernel -> bit-identical numerics.
// If the compiler misses <=64 regs, occupancy falls back to 16 waves/CU
// (status quo) -- bounded downside; VGPR_Count in counters is the gate.
// MODE 0 (GEMM1): A=Xb8 token-order; C = fp8(relu(acc)*0.125) scattered via
//                 invperm, k-rotated by bucket position p.
// MODE 1 (GEMM2): A=Xff8 bucket-order; B per bucket via po[]; epilogue via
//                 perm: Xb[tok] = bf16(Xb[tok]+relu(acc)/512)
template <int MODE>
__global__ __launch_bounds__(1024, 8)
void gemm_fp8_kernel(const unsigned char* __restrict__ A,
                     const unsigned char* __restrict__ B,
                     void* __restrict__ Cout,
                     const unsigned short* __restrict__ xres,
                     const int* __restrict__ pmap,   // MODE0: invperm, MODE1: perm
                     const int* __restrict__ po,     // MODE1 only: padded offsets[9]
                     int K, int ldA) {
    __shared__ unsigned char As[128 * 128];
    __shared__ unsigned char Bs[128 * 128];
    __shared__ int ptile[128];

    const int tid  = threadIdx.x;
    const int wave = tid >> 6;          // 0..15
    const int lane = tid & 63;
    const int quad = lane >> 4;
    const int tl   = lane & 15;
    int m0, n0;
    if constexpr (MODE == 1) {
        // 1056 blocks; XCD-band swizzle (1056 % 8 == 0, bijective)
        const int sid = (blockIdx.x & 7) * 132 + (blockIdx.x >> 3);
        m0 = (sid >> 2) * 128;
        n0 = (sid & 3) * 128;
    } else {
        // 2048 blocks; XCD-band swizzle: XCD k owns 32 m-tiles x all 8 n-tiles
        const int sid = (blockIdx.x & 7) * 256 + (blockIdx.x >> 3);
        m0 = (sid >> 3) * 128;
        n0 = (sid & 7) * 128;
    }
    const int wm = (wave >> 2) * 32;    // 4x4 wave grid, 32x32 out each
    const int wn = (wave & 3) * 32;

    const unsigned char* Bp = B;
    if constexpr (MODE == 1) {
        if (m0 >= po[8]) return;                  // fully-padded tail block
        int bsel = 0;
        #pragma unroll
        for (int i = 1; i < 8; i++) bsel += (m0 >= po[i]) ? 1 : 0;
        Bp = B + (size_t)bsel * (DIN * DFF);
    }
    if (tid < 128) ptile[tid] = pmap[m0 + tid];

    f32x4 acc[2][2];
    #pragma unroll
    for (int i = 0; i < 2; i++)
        #pragma unroll
        for (int j = 0; j < 2; j++)
            acc[i][j] = (f32x4){0.f, 0.f, 0.f, 0.f};

    // staging: chunk c = tid (1024 chunks of 16B per 128x128 tile)
    const int arow = tid >> 3;          // 0..127
    const int aj   = (tid & 7) * 16;    // 0..112
    const unsigned char* aptr = A + (size_t)(m0 + arow) * ldA + aj;
    const unsigned char* bptr = Bp + (size_t)(n0 + arow) * K + aj;

    for (int k0 = 0; k0 < K; k0 += 128) {
        __syncthreads();
        async16(aptr + k0, (char*)As + tid * 16);
        async16(bptr + k0, (char*)Bs + tid * 16);
        __syncthreads();

        #pragma unroll
        for (int ks = 0; ks < 4; ks++) {
            long af[2], bfr[2];
            const int o = (ks * 32 + quad * 8 + tl * 8) & 127;  // rotated frag offset
            #pragma unroll
            for (int t = 0; t < 2; t++)
                af[t] = *(const long*)(As + (wm + t * 16 + tl) * 128 + o);
            #pragma unroll
            for (int t = 0; t < 2; t++)
                bfr[t] = *(const long*)(Bs + (wn + t * 16 + tl) * 128 + o);
            #pragma unroll
            for (int mt = 0; mt < 2; mt++)
                #pragma unroll
                for (int nt = 0; nt < 2; nt++)
                    acc[mt][nt] = __builtin_amdgcn_mfma_f32_16x16x32_fp8_fp8(
                        bfr[nt], af[mt], acc[mt][nt], 0, 0, 0);  // swapped: D[n][tok]
        }
    }

    // epilogue: lane holds 4 consecutive n (regs) for token tl
    if constexpr (MODE == 0) {
        unsigned char* C8 = (unsigned char*)Cout;
        #pragma unroll
        for (int mt = 0; mt < 2; mt++) {
            const int p = ptile[wm + mt * 16 + tl];            // bucket position
            const size_t rowbase = (size_t)p * DFF;
            const int prot = (p & 15) << 3;
            #pragma unroll
            for (int nt = 0; nt < 2; nt++) {
                const int off = wn + nt * 16 + quad * 4;       // in-window offset
                unsigned int pk = pk4_fp8(fmaxf(acc[mt][nt][0], 0.f) * 0.125f,
                                          fmaxf(acc[mt][nt][1], 0.f) * 0.125f,
                                          fmaxf(acc[mt][nt][2], 0.f) * 0.125f,
                                          fmaxf(acc[mt][nt][3], 0.f) * 0.125f);
                const int phys = (off & ~127) + (((off & 127) + prot) & 127);
                *(unsigned int*)(C8 + rowbase + n0 + phys) = pk;
            }
        }
    } else {
        unsigned short* Cb = (unsigned short*)Cout;
        int toks[2];
        #pragma unroll
        for (int mt = 0; mt < 2; mt++) toks[mt] = ptile[wm + mt * 16 + tl];
        // batch residual loads first (breaks serial dependent chains)
        ushort4 rv[2][2];
        #pragma unroll
        for (int mt = 0; mt < 2; mt++) {
            if (toks[mt] < 0) continue;
            const size_t rowbase = (size_t)toks[mt] * DIN;
            #pragma unroll
            for (int nt = 0; nt < 2; nt++)
                rv[mt][nt] = *(const ushort4*)(xres + rowbase + n0 + wn + nt * 16 + quad * 4);
        }
        #pragma unroll
        for (int mt = 0; mt < 2; mt++) {
            if (toks[mt] < 0) continue;
            const size_t rowbase = (size_t)toks[mt] * DIN;
            #pragma unroll
            for (int nt = 0; nt < 2; nt++) {
                const int ncol = n0 + wn + nt * 16 + quad * 4;
                ushort4 o;
                o.x = f2bf(bf2f(rv[mt][nt].x) + fmaxf(acc[mt][nt][0], 0.f) * 0.001953125f);
                o.y = f2bf(bf2f(rv[mt][nt].y) + fmaxf(acc[mt][nt][1], 0.f) * 0.001953125f);
                o.z = f2bf(bf2f(rv[mt][nt].z) + fmaxf(acc[mt][nt][2], 0.f) * 0.001953125f);
                o.w = f2bf(bf2f(rv[mt][nt].w) + fmaxf(acc[mt][nt][3], 0.f) * 0.001953125f);
                *(ushort4*)(Cb + rowbase + ncol) = o;
            }
        }
    }
}

// ------- bf16 GEMM3 + head (kept full precision): 128x256 tile, 512 thr --------
// out[tok] += relu(Xb @ W_c1) . w2   (atomicAdd partials per n-block)
// 1D grid + XCD-band swizzle (512 % 8 == 0). Untouched this round.
__global__ __launch_bounds__(512, 4)
void gemm3_kernel(const unsigned short* __restrict__ A,
                  const unsigned short* __restrict__ B,
                  const float* __restrict__ w2,
                  float* __restrict__ outp,
                  int K, int ldA) {
    __shared__ unsigned short As[128 * 64];
    __shared__ unsigned short Bs[256 * 64];

    const int tid  = threadIdx.x;
    const int wave = tid >> 6;
    const int lane = tid & 63;
    const int quad = lane >> 4;
    const int tl   = lane & 15;
    const int sid = (blockIdx.x & 7) * 64 + (blockIdx.x >> 3);
    const int m0 = (sid >> 1) * 128;
    const int n0 = (sid & 1) * 256;
    const int wm = (wave & 1) * 64;
    const int wn = (wave >> 1) * 64;

    f32x4 acc[4][4];
    #pragma unroll
    for (int i = 0; i < 4; i++)
        #pragma unroll
        for (int j = 0; j < 4; j++)
            acc[i][j] = (f32x4){0.f, 0.f, 0.f, 0.f};

    for (int k0 = 0; k0 < K; k0 += 64) {
        __syncthreads();
        #pragma unroll
        for (int i = 0; i < 2; i++) {
            const int c   = (i * 8 + wave) * 64 + lane;
            const int row = c >> 3;
            const int gj  = (c & 7) ^ (row & 7);
            async16(A + (size_t)(m0 + row) * ldA + k0 + gj * 8, (char*)As + (size_t)c * 16);
        }
        #pragma unroll
        for (int i = 0; i < 4; i++) {
            const int c   = (i * 8 + wave) * 64 + lane;
            const int row = c >> 3;
            const int gj  = (c & 7) ^ (row & 7);
            async16(B + (size_t)(n0 + row) * K + k0 + gj * 8, (char*)Bs + (size_t)c * 16);
        }
        __syncthreads();

        #pragma unroll
        for (int ks = 0; ks < 2; ks++) {
            bf16x8 af[4], bfr[4];
            const int jc = ks * 4 + quad;
            #pragma unroll
            for (int t = 0; t < 4; t++) {
                const int r = wm + t * 16 + tl;
                af[t] = *(const bf16x8*)(As + (r * 8 + (jc ^ (r & 7))) * 8);
            }
            #pragma unroll
            for (int t = 0; t < 4; t++) {
                const int r = wn + t * 16 + tl;
                bfr[t] = *(const bf16x8*)(Bs + (r * 8 + (jc ^ (r & 7))) * 8);
            }
            #pragma unroll
            for (int mt = 0; mt < 4; mt++)
                #pragma unroll
                for (int nt = 0; nt < 4; nt++)
                    acc[mt][nt] = __builtin_amdgcn_mfma_f32_16x16x32_bf16(
                        bfr[nt], af[mt], acc[mt][nt], 0, 0, 0);
        }
    }

    float4 w2v[4];
    #pragma unroll
    for (int nt = 0; nt < 4; nt++)
        w2v[nt] = *(const float4*)(w2 + n0 + wn + nt * 16 + quad * 4);
    #pragma unroll
    for (int mt = 0; mt < 4; mt++) {
        float s = 0.f;
        #pragma unroll
        for (int nt = 0; nt < 4; nt++) {
            s += fmaxf(acc[mt][nt][0], 0.f) * w2v[nt].x;
            s += fmaxf(acc[mt][nt][1], 0.f) * w2v[nt].y;
            s += fmaxf(acc[mt][nt][2], 0.f) * w2v[nt].z;
            s += fmaxf(acc[mt][nt][3], 0.f) * w2v[nt].w;
        }
        s += __shfl_down(s, 32);
        s += __shfl_down(s, 16);
        if (lane < 16) atomicAdd(&outp[m0 + wm + mt * 16 + lane], s);
    }
}

extern "C" void kernel_launch(void* const* d_in, const int* in_sizes, int n_in,
                              void* d_out, int out_size, void* d_ws, size_t ws_size,
                              hipStream_t stream) {
    const float* x      = (const float*)d_in[0];
    const int*   types  = (const int*)d_in[1];
    const float* W_pre  = (const float*)d_in[2];
    const float* W_types= (const float*)d_in[3];
    const float* W_c1   = (const float*)d_in[4];
    const float* W_c2   = (const float*)d_in[5];
    float* out = (float*)d_out;

    // workspace layout (~91 MB):
    char* ws = (char*)d_ws;
    unsigned short* Xb  = (unsigned short*)(ws);                    // bf16 [32768][512], becomes X_res
    unsigned char*  Xff8= (unsigned char*)(ws + 33554432ull);       // fp8 [MPAD][1024] = 8*x_, bucket order, k-rotated
    unsigned char*  Xb8 = (unsigned char*)(ws + 68157440ull);       // fp8 [32768][512] = x, k-rotated
    unsigned char*  Wp8 = (unsigned char*)(ws + 84934656ull);       // fp8 [1024][512] (x64, rotated)
    unsigned char*  Wt8 = (unsigned char*)(ws + 85458944ull);       // fp8 [8][512][1024] (x64, rotated)
    unsigned short* WcT = (unsigned short*)(ws + 89653248ull);      // bf16 [512][512]
    int* perm           = (int*)(ws + 90177536ull);                  // MPAD ints
    int* invperm        = (int*)(ws + 90312704ull);                  // N_TOK ints
    int* po             = (int*)(ws + 90443776ull);                  // 9 ints (padded offsets)
    int* blockhist      = po + 16;                                   // 64*8 ints

    // 1) merged prep: tokens [0,16384), weights [16384,26624), perm-pad [26624,26756)
    prep_kernel<<<26756, 256, 0, stream>>>(x, Xb, Xb8, types, blockhist,
                                           W_pre, W_types, W_c1, Wp8, Wt8, WcT, perm);
    // 2) deterministic scatter + po publish + out zero
    scatter_kernel<<<64, 512, 0, stream>>>(types, blockhist, perm, invperm, out, po);
    // 3) GEMM1 (fp8, 16-wave 128^2, XCD-banded): Xff8[invperm[tok]] = fp8(8 * relu(x @ W_pre))
    gemm_fp8_kernel<0><<<2048, 1024, 0, stream>>>(
        Xb8, Wp8, Xff8, nullptr, invperm, nullptr, 512, 512);
    // 4) GEMM2 (fp8, routed, 16-wave 128^2, XCD-banded): Xb = bf16(Xb + relu(Xff8 @ Wt8[b]) / 512)
    gemm_fp8_kernel<1><<<1056, 1024, 0, stream>>>(
        Xff8, Wt8, Xb, Xb, perm, po, 1024, 1024);
    // 5) GEMM3 + head (bf16, XCD-banded 1D grid): out = relu(Xb @ W_c1) @ W_c2
    gemm3_kernel<<<512, 512, 0, stream>>>(
        Xb, WcT, W_c2, out, 512, 512);
}